// Round 1
// baseline (180.627 us; speedup 1.0000x reference)
//
#include <hip/hip_runtime.h>
#include <cstdint>
#include <cstddef>

typedef unsigned short u16;
typedef __attribute__((ext_vector_type(4))) float f32x4;
typedef __attribute__((ext_vector_type(8))) short bf16x8;

#define LN_EPS 1e-5f

__device__ __forceinline__ u16 f2bf(float f) {
  unsigned int u = __float_as_uint(f);
  u += 0x7FFFu + ((u >> 16) & 1u);
  return (u16)(u >> 16);
}

__device__ __forceinline__ float l0gate(float loga) {
  float s = 1.0f / (1.0f + expf(-loga));
  float v = s * 1.2f - 0.1f;   // sigmoid*(zeta-gamma)+gamma, zeta=1.1 gamma=-0.1
  return fminf(fmaxf(v, 0.0f), 1.0f);
}

__device__ __forceinline__ void llds16(u16* lds, const u16* g) {
  __builtin_amdgcn_global_load_lds(
      (const __attribute__((address_space(1))) unsigned int*)g,
      (__attribute__((address_space(3))) unsigned int*)lds, 16, 0, 0);
}

// ---- prep: fold L0 gate into bf16 weights ----
// i in [0, 2^20): handles one down_w elem and one up_w elem
__global__ __launch_bounds__(256) void prep_weights(
    const float* __restrict__ dw, const float* __restrict__ uw,
    const float* __restrict__ dloga, const float* __restrict__ uloga,
    const int* __restrict__ lang,
    u16* __restrict__ dwb, u16* __restrict__ uwb) {
  const int lid = lang[0];
  const unsigned i = blockIdx.x * 256u + threadIdx.x;
  // down_w [512][2048]: gate indexed by input feature d = i % 2048
  dwb[i] = f2bf(dw[i] * l0gate(dloga[lid * 2048 + (i & 2047u)]));
  // up_w [2048][512]: gate indexed by bottleneck k = i % 512
  uwb[i] = f2bf(uw[i] * l0gate(uloga[lid * 512 + (i & 511u)]));
}

// ---- LayerNorm over D=2048 + bf16 cast; one block per token row ----
__global__ __launch_bounds__(256) void ln_kernel(
    const float* __restrict__ x, const float* __restrict__ g,
    const float* __restrict__ b, u16* __restrict__ h1) {
  const int row = blockIdx.x;
  const int tid = threadIdx.x;
  const float4* xr = (const float4*)(x + (size_t)row * 2048);
  float4 v0 = xr[tid * 2 + 0];
  float4 v1 = xr[tid * 2 + 1];
  float s = v0.x + v0.y + v0.z + v0.w + v1.x + v1.y + v1.z + v1.w;
  float q = v0.x * v0.x + v0.y * v0.y + v0.z * v0.z + v0.w * v0.w +
            v1.x * v1.x + v1.y * v1.y + v1.z * v1.z + v1.w * v1.w;
#pragma unroll
  for (int off = 32; off > 0; off >>= 1) {
    s += __shfl_down(s, off, 64);
    q += __shfl_down(q, off, 64);
  }
  __shared__ float ss[4], sq[4], sstat[2];
  const int wave = tid >> 6, lane = tid & 63;
  if (lane == 0) { ss[wave] = s; sq[wave] = q; }
  __syncthreads();
  if (tid == 0) {
    float S = ss[0] + ss[1] + ss[2] + ss[3];
    float Q = sq[0] + sq[1] + sq[2] + sq[3];
    float mu = S * (1.0f / 2048.0f);
    float var = Q * (1.0f / 2048.0f) - mu * mu;
    sstat[0] = mu;
    sstat[1] = rsqrtf(var + LN_EPS);
  }
  __syncthreads();
  const float mu = sstat[0], rs = sstat[1];
  const float4* g4 = (const float4*)g;
  const float4* b4 = (const float4*)b;
  float4 ga = g4[tid * 2], gb = g4[tid * 2 + 1];
  float4 ba = b4[tid * 2], bb = b4[tid * 2 + 1];
  union { u16 us[8]; uint4 u; } p;
  p.us[0] = f2bf((v0.x - mu) * rs * ga.x + ba.x);
  p.us[1] = f2bf((v0.y - mu) * rs * ga.y + ba.y);
  p.us[2] = f2bf((v0.z - mu) * rs * ga.z + ba.z);
  p.us[3] = f2bf((v0.w - mu) * rs * ga.w + ba.w);
  p.us[4] = f2bf((v1.x - mu) * rs * gb.x + bb.x);
  p.us[5] = f2bf((v1.y - mu) * rs * gb.y + bb.y);
  p.us[6] = f2bf((v1.z - mu) * rs * gb.z + bb.z);
  p.us[7] = f2bf((v1.w - mu) * rs * gb.w + bb.w);
  ((uint4*)(h1 + (size_t)row * 2048))[tid] = p.u;
}

// ---- m97-structure bf16 GEMM: C[M,N] = A[M,K] * B[N,K]^T, K-contiguous both ----
// EPI=1: +bias, relu, bf16 store.  EPI=2: +bias +resid, f32 store.
template <int EPI>
__global__ void gemm_bt(const u16* __restrict__ A, const u16* __restrict__ B,
                        int M, int N, int K,
                        const float* __restrict__ bias,
                        const float* __restrict__ resid,
                        void* __restrict__ outp) {
  __shared__ u16 As[128 * 64];
  __shared__ u16 Bs[128 * 64];
  const int tid = threadIdx.x;
  const int wave = tid >> 6, lane = tid & 63;
  const int wr = (wave >> 1) * 64;   // wave row offset in tile
  const int wc = (wave & 1) * 64;    // wave col offset in tile
  const int lrow = lane & 15, lk = lane >> 4;
  const size_t m0 = (size_t)blockIdx.y * 128;
  const size_t n0 = (size_t)blockIdx.x * 128;
  const int srow = lane >> 3;        // staging: row within 8-row segment
  const int scol = (lane & 7) * 8;   // staging: col (bf16 elems)

  f32x4 acc[4][4] = {};

  for (int k0 = 0; k0 < K; k0 += 64) {
    // stage A,B tiles (128x64 bf16 each) via global_load_lds width 16
#pragma unroll
    for (int c = 0; c < 4; ++c) {
      const int seg = c * 4 + wave;          // 0..15, each = 8 rows
      const int r = seg * 8 + srow;
      llds16(&As[seg * 512], A + (m0 + r) * (size_t)K + (k0 + scol));
      llds16(&Bs[seg * 512], B + (n0 + r) * (size_t)K + (k0 + scol));
    }
    __syncthreads();  // compiler emits vmcnt(0) before barrier -> LDS ready
#pragma unroll
    for (int ks = 0; ks < 2; ++ks) {
      bf16x8 af[4], bfr[4];
#pragma unroll
      for (int m = 0; m < 4; ++m)
        af[m] = *(const bf16x8*)&As[(wr + m * 16 + lrow) * 64 + ks * 32 + lk * 8];
#pragma unroll
      for (int n = 0; n < 4; ++n)
        bfr[n] = *(const bf16x8*)&Bs[(wc + n * 16 + lrow) * 64 + ks * 32 + lk * 8];
#pragma unroll
      for (int m = 0; m < 4; ++m)
#pragma unroll
        for (int n = 0; n < 4; ++n)
          acc[m][n] = __builtin_amdgcn_mfma_f32_16x16x32_bf16(af[m], bfr[n],
                                                              acc[m][n], 0, 0, 0);
    }
    __syncthreads();  // all waves done reading before next stage overwrites
  }

  // epilogue: D row i = 4*(lane>>4)+reg (M dim), col j = lane&15 (N dim)
#pragma unroll
  for (int m = 0; m < 4; ++m) {
    const size_t row_base = m0 + wr + m * 16 + lk * 4;
#pragma unroll
    for (int n = 0; n < 4; ++n) {
      const size_t col = n0 + wc + n * 16 + lrow;
      const float bv = bias[col];
#pragma unroll
      for (int r = 0; r < 4; ++r) {
        const size_t row = row_base + r;
        float v = acc[m][n][r] + bv;
        if (EPI == 1) {
          v = fmaxf(v, 0.0f);
          ((u16*)outp)[row * (size_t)N + col] = f2bf(v);
        } else {
          v += resid[row * (size_t)N + col];
          ((float*)outp)[row * (size_t)N + col] = v;
        }
      }
    }
  }
}

extern "C" void kernel_launch(void* const* d_in, const int* in_sizes, int n_in,
                              void* d_out, int out_size, void* d_ws, size_t ws_size,
                              hipStream_t stream) {
  const float* x         = (const float*)d_in[0];
  const float* down_w    = (const float*)d_in[1];
  const float* down_b    = (const float*)d_in[2];
  const float* up_w      = (const float*)d_in[3];
  const float* up_b      = (const float*)d_in[4];
  const float* ln_g      = (const float*)d_in[5];
  const float* ln_b      = (const float*)d_in[6];
  const float* down_loga = (const float*)d_in[7];
  const float* up_loga   = (const float*)d_in[8];
  const int*   lang      = (const int*)d_in[9];

  const int D = 2048, BNK = 512;
  const int M = in_sizes[0] / D;  // 16384

  char* ws = (char*)d_ws;
  u16* h1  = (u16*)ws;                                   // [M][D] bf16
  u16* h2  = (u16*)(ws + (size_t)M * D * 2);             // [M][BNK] bf16
  u16* dwb = (u16*)(ws + (size_t)M * D * 2 + (size_t)M * BNK * 2);  // [BNK][D]
  u16* uwb = dwb + (size_t)BNK * D;                      // [D][BNK]

  prep_weights<<<(BNK * D) / 256, 256, 0, stream>>>(down_w, up_w, down_loga,
                                                    up_loga, lang, dwb, uwb);
  ln_kernel<<<M, 256, 0, stream>>>(x, ln_g, ln_b, h1);
  gemm_bt<1><<<dim3(BNK / 128, M / 128), 256, 0, stream>>>(
      h1, dwb, M, BNK, D, down_b, nullptr, h2);
  gemm_bt<2><<<dim3(D / 128, M / 128), 256, 0, stream>>>(
      h2, uwb, M, D, BNK, up_b, x, d_out);
}

// Round 2
// 178.746 us; speedup vs baseline: 1.0105x; 1.0105x over previous
//
#include <hip/hip_runtime.h>
#include <cstdint>
#include <cstddef>

typedef unsigned short u16;
typedef __attribute__((ext_vector_type(4))) float f32x4;
typedef __attribute__((ext_vector_type(8))) short bf16x8;

#define LN_EPS 1e-5f

__device__ __forceinline__ u16 f2bf(float f) {
  unsigned int u = __float_as_uint(f);
  u += 0x7FFFu + ((u >> 16) & 1u);
  return (u16)(u >> 16);
}

__device__ __forceinline__ float l0gate(float loga) {
  float s = 1.0f / (1.0f + expf(-loga));
  float v = s * 1.2f - 0.1f;   // sigmoid*(zeta-gamma)+gamma, zeta=1.1 gamma=-0.1
  return fminf(fmaxf(v, 0.0f), 1.0f);
}

__device__ __forceinline__ void llds16(u16* lds, const u16* g) {
  __builtin_amdgcn_global_load_lds(
      (const __attribute__((address_space(1))) unsigned int*)g,
      (__attribute__((address_space(3))) unsigned int*)lds, 16, 0, 0);
}

// ---- prep: fold L0 gate into bf16 weights ----
__global__ __launch_bounds__(256) void prep_weights(
    const float* __restrict__ dw, const float* __restrict__ uw,
    const float* __restrict__ dloga, const float* __restrict__ uloga,
    const int* __restrict__ lang,
    u16* __restrict__ dwb, u16* __restrict__ uwb) {
  const int lid = lang[0];
  const unsigned i = blockIdx.x * 256u + threadIdx.x;
  dwb[i] = f2bf(dw[i] * l0gate(dloga[lid * 2048 + (i & 2047u)]));
  uwb[i] = f2bf(uw[i] * l0gate(uloga[lid * 512 + (i & 511u)]));
}

// ---- LayerNorm over D=2048 + bf16 cast; one block per token row ----
__global__ __launch_bounds__(256) void ln_kernel(
    const float* __restrict__ x, const float* __restrict__ g,
    const float* __restrict__ b, u16* __restrict__ h1) {
  const int row = blockIdx.x;
  const int tid = threadIdx.x;
  const float4* xr = (const float4*)(x + (size_t)row * 2048);
  float4 v0 = xr[tid * 2 + 0];
  float4 v1 = xr[tid * 2 + 1];
  float s = v0.x + v0.y + v0.z + v0.w + v1.x + v1.y + v1.z + v1.w;
  float q = v0.x * v0.x + v0.y * v0.y + v0.z * v0.z + v0.w * v0.w +
            v1.x * v1.x + v1.y * v1.y + v1.z * v1.z + v1.w * v1.w;
#pragma unroll
  for (int off = 32; off > 0; off >>= 1) {
    s += __shfl_down(s, off, 64);
    q += __shfl_down(q, off, 64);
  }
  __shared__ float ss[4], sq[4], sstat[2];
  const int wave = tid >> 6, lane = tid & 63;
  if (lane == 0) { ss[wave] = s; sq[wave] = q; }
  __syncthreads();
  if (tid == 0) {
    float S = ss[0] + ss[1] + ss[2] + ss[3];
    float Q = sq[0] + sq[1] + sq[2] + sq[3];
    float mu = S * (1.0f / 2048.0f);
    float var = Q * (1.0f / 2048.0f) - mu * mu;
    sstat[0] = mu;
    sstat[1] = rsqrtf(var + LN_EPS);
  }
  __syncthreads();
  const float mu = sstat[0], rs = sstat[1];
  const float4* g4 = (const float4*)g;
  const float4* b4 = (const float4*)b;
  float4 ga = g4[tid * 2], gb = g4[tid * 2 + 1];
  float4 ba = b4[tid * 2], bb = b4[tid * 2 + 1];
  union { u16 us[8]; uint4 u; } p;
  p.us[0] = f2bf((v0.x - mu) * rs * ga.x + ba.x);
  p.us[1] = f2bf((v0.y - mu) * rs * ga.y + ba.y);
  p.us[2] = f2bf((v0.z - mu) * rs * ga.z + ba.z);
  p.us[3] = f2bf((v0.w - mu) * rs * ga.w + ba.w);
  p.us[4] = f2bf((v1.x - mu) * rs * gb.x + bb.x);
  p.us[5] = f2bf((v1.y - mu) * rs * gb.y + bb.y);
  p.us[6] = f2bf((v1.z - mu) * rs * gb.z + bb.z);
  p.us[7] = f2bf((v1.w - mu) * rs * gb.w + bb.w);
  ((uint4*)(h1 + (size_t)row * 2048))[tid] = p.u;
}

// ---- 2-phase double-buffered bf16 GEMM: C[M,N] = A[M,K] * B[N,K]^T ----
// EPI=1: +bias, relu, bf16 store.  EPI=2: +bias +resid, f32 store.
template <int EPI>
__global__ __launch_bounds__(256) void gemm_bt(
    const u16* __restrict__ A, const u16* __restrict__ B,
    int M, int N, int K,
    const float* __restrict__ bias,
    const float* __restrict__ resid,
    void* __restrict__ outp) {
  __shared__ u16 As[2][128 * 64];
  __shared__ u16 Bs[2][128 * 64];
  const int tid = threadIdx.x;
  const int wave = tid >> 6, lane = tid & 63;
  const int wr = (wave >> 1) * 64;   // wave row offset in tile
  const int wc = (wave & 1) * 64;    // wave col offset in tile
  const int lrow = lane & 15, lk = lane >> 4;
  const size_t m0 = (size_t)blockIdx.y * 128;
  const size_t n0 = (size_t)blockIdx.x * 128;
  const int srow = lane >> 3;        // staging: row within 8-row segment
  const int scol = (lane & 7) * 8;   // staging: col (bf16 elems)

  f32x4 acc[4][4] = {};

  // stage K-tile t into buffer buf (A,B: 128x64 bf16 each, width-16 lds loads)
  auto STAGE = [&](int buf, int k0) {
#pragma unroll
    for (int c = 0; c < 4; ++c) {
      const int seg = c * 4 + wave;          // 0..15, each = 8 rows
      const int r = seg * 8 + srow;
      llds16(&As[buf][seg * 512], A + (m0 + r) * (size_t)K + (k0 + scol));
      llds16(&Bs[buf][seg * 512], B + (n0 + r) * (size_t)K + (k0 + scol));
    }
  };

  // prologue: fill buffer 0, drain, barrier
  STAGE(0, 0);
  __syncthreads();

  int cur = 0;
  for (int k0 = 0; k0 < K; k0 += 64) {
    // issue next tile's staging FIRST -> latency hides under compute
    if (k0 + 64 < K) STAGE(cur ^ 1, k0 + 64);

    const u16* Ab = &As[cur][0];
    const u16* Bb = &Bs[cur][0];
#pragma unroll
    for (int ks = 0; ks < 2; ++ks) {
      bf16x8 af[4], bfr[4];
#pragma unroll
      for (int m = 0; m < 4; ++m)
        af[m] = *(const bf16x8*)&Ab[(wr + m * 16 + lrow) * 64 + ks * 32 + lk * 8];
#pragma unroll
      for (int n = 0; n < 4; ++n)
        bfr[n] = *(const bf16x8*)&Bb[(wc + n * 16 + lrow) * 64 + ks * 32 + lk * 8];
      __builtin_amdgcn_s_setprio(1);
#pragma unroll
      for (int m = 0; m < 4; ++m)
#pragma unroll
        for (int n = 0; n < 4; ++n)
          acc[m][n] = __builtin_amdgcn_mfma_f32_16x16x32_bf16(af[m], bfr[n],
                                                              acc[m][n], 0, 0, 0);
      __builtin_amdgcn_s_setprio(0);
    }
    // single barrier per K-step: compiler emits vmcnt(0) lgkmcnt(0) drain here,
    // guaranteeing (a) next buffer fully staged, (b) all waves done reading cur
    __syncthreads();
    cur ^= 1;
  }

  // epilogue: D row i = 4*(lane>>4)+reg (M dim), col j = lane&15 (N dim)
#pragma unroll
  for (int m = 0; m < 4; ++m) {
    const size_t row_base = m0 + wr + m * 16 + lk * 4;
#pragma unroll
    for (int n = 0; n < 4; ++n) {
      const size_t col = n0 + wc + n * 16 + lrow;
      const float bv = bias[col];
#pragma unroll
      for (int r = 0; r < 4; ++r) {
        const size_t row = row_base + r;
        float v = acc[m][n][r] + bv;
        if (EPI == 1) {
          v = fmaxf(v, 0.0f);
          ((u16*)outp)[row * (size_t)N + col] = f2bf(v);
        } else {
          v += resid[row * (size_t)N + col];
          ((float*)outp)[row * (size_t)N + col] = v;
        }
      }
    }
  }
}

extern "C" void kernel_launch(void* const* d_in, const int* in_sizes, int n_in,
                              void* d_out, int out_size, void* d_ws, size_t ws_size,
                              hipStream_t stream) {
  const float* x         = (const float*)d_in[0];
  const float* down_w    = (const float*)d_in[1];
  const float* down_b    = (const float*)d_in[2];
  const float* up_w      = (const float*)d_in[3];
  const float* up_b      = (const float*)d_in[4];
  const float* ln_g      = (const float*)d_in[5];
  const float* ln_b      = (const float*)d_in[6];
  const float* down_loga = (const float*)d_in[7];
  const float* up_loga   = (const float*)d_in[8];
  const int*   lang      = (const int*)d_in[9];

  const int D = 2048, BNK = 512;
  const int M = in_sizes[0] / D;  // 16384

  char* ws = (char*)d_ws;
  u16* h1  = (u16*)ws;                                   // [M][D] bf16
  u16* h2  = (u16*)(ws + (size_t)M * D * 2);             // [M][BNK] bf16
  u16* dwb = (u16*)(ws + (size_t)M * D * 2 + (size_t)M * BNK * 2);  // [BNK][D]
  u16* uwb = dwb + (size_t)BNK * D;                      // [D][BNK]

  prep_weights<<<(BNK * D) / 256, 256, 0, stream>>>(down_w, up_w, down_loga,
                                                    up_loga, lang, dwb, uwb);
  ln_kernel<<<M, 256, 0, stream>>>(x, ln_g, ln_b, h1);
  gemm_bt<1><<<dim3(BNK / 128, M / 128), 256, 0, stream>>>(
      h1, dwb, M, BNK, D, down_b, nullptr, h2);
  gemm_bt<2><<<dim3(D / 128, M / 128), 256, 0, stream>>>(
      h2, uwb, M, D, BNK, up_b, x, d_out);
}

// Round 3
// 159.299 us; speedup vs baseline: 1.1339x; 1.1221x over previous
//
#include <hip/hip_runtime.h>
#include <cstdint>
#include <cstddef>

typedef unsigned short u16;
typedef __attribute__((ext_vector_type(4))) float f32x4;
typedef __attribute__((ext_vector_type(8))) short bf16x8;

#define LN_EPS 1e-5f

__device__ __forceinline__ u16 f2bf(float f) {
  unsigned int u = __float_as_uint(f);
  u += 0x7FFFu + ((u >> 16) & 1u);
  return (u16)(u >> 16);
}

__device__ __forceinline__ float l0gate(float loga) {
  float s = 1.0f / (1.0f + expf(-loga));
  float v = s * 1.2f - 0.1f;   // sigmoid*(zeta-gamma)+gamma, zeta=1.1 gamma=-0.1
  return fminf(fmaxf(v, 0.0f), 1.0f);
}

__device__ __forceinline__ void llds16(u16* lds, const u16* g) {
  __builtin_amdgcn_global_load_lds(
      (const __attribute__((address_space(1))) unsigned int*)g,
      (__attribute__((address_space(3))) unsigned int*)lds, 16, 0, 0);
}

// ---- prep: fold L0 gate into bf16 weights ----
__global__ __launch_bounds__(256) void prep_weights(
    const float* __restrict__ dw, const float* __restrict__ uw,
    const float* __restrict__ dloga, const float* __restrict__ uloga,
    const int* __restrict__ lang,
    u16* __restrict__ dwb, u16* __restrict__ uwb) {
  const int lid = lang[0];
  const unsigned i = blockIdx.x * 256u + threadIdx.x;
  dwb[i] = f2bf(dw[i] * l0gate(dloga[lid * 2048 + (i & 2047u)]));
  uwb[i] = f2bf(uw[i] * l0gate(uloga[lid * 512 + (i & 511u)]));
}

// ---- LayerNorm over D=2048 + bf16 cast; one block per token row ----
__global__ __launch_bounds__(256) void ln_kernel(
    const float* __restrict__ x, const float* __restrict__ g,
    const float* __restrict__ b, u16* __restrict__ h1) {
  const int row = blockIdx.x;
  const int tid = threadIdx.x;
  const float4* xr = (const float4*)(x + (size_t)row * 2048);
  float4 v0 = xr[tid * 2 + 0];
  float4 v1 = xr[tid * 2 + 1];
  float s = v0.x + v0.y + v0.z + v0.w + v1.x + v1.y + v1.z + v1.w;
  float q = v0.x * v0.x + v0.y * v0.y + v0.z * v0.z + v0.w * v0.w +
            v1.x * v1.x + v1.y * v1.y + v1.z * v1.z + v1.w * v1.w;
#pragma unroll
  for (int off = 32; off > 0; off >>= 1) {
    s += __shfl_down(s, off, 64);
    q += __shfl_down(q, off, 64);
  }
  __shared__ float ss[4], sq[4], sstat[2];
  const int wave = tid >> 6, lane = tid & 63;
  if (lane == 0) { ss[wave] = s; sq[wave] = q; }
  __syncthreads();
  if (tid == 0) {
    float S = ss[0] + ss[1] + ss[2] + ss[3];
    float Q = sq[0] + sq[1] + sq[2] + sq[3];
    float mu = S * (1.0f / 2048.0f);
    float var = Q * (1.0f / 2048.0f) - mu * mu;
    sstat[0] = mu;
    sstat[1] = rsqrtf(var + LN_EPS);
  }
  __syncthreads();
  const float mu = sstat[0], rs = sstat[1];
  const float4* g4 = (const float4*)g;
  const float4* b4 = (const float4*)b;
  float4 ga = g4[tid * 2], gb = g4[tid * 2 + 1];
  float4 ba = b4[tid * 2], bb = b4[tid * 2 + 1];
  union { u16 us[8]; uint4 u; } p;
  p.us[0] = f2bf((v0.x - mu) * rs * ga.x + ba.x);
  p.us[1] = f2bf((v0.y - mu) * rs * ga.y + ba.y);
  p.us[2] = f2bf((v0.z - mu) * rs * ga.z + ba.z);
  p.us[3] = f2bf((v0.w - mu) * rs * ga.w + ba.w);
  p.us[4] = f2bf((v1.x - mu) * rs * gb.x + bb.x);
  p.us[5] = f2bf((v1.y - mu) * rs * gb.y + bb.y);
  p.us[6] = f2bf((v1.z - mu) * rs * gb.z + bb.z);
  p.us[7] = f2bf((v1.w - mu) * rs * gb.w + bb.w);
  ((uint4*)(h1 + (size_t)row * 2048))[tid] = p.u;
}

// ---- dbuf bf16 GEMM, counted-vmcnt pipeline + T2 swizzle + T1 XCD swizzle ----
// C[M,N] = A[M,K] * B[N,K]^T, both K-contiguous.
// EPI=1: +bias, relu, bf16 store.  EPI=2: +bias +resid, f32 store.
// 1-D grid (nwg = (M/128)*(N/128), must be %8==0); NX = N/128.
template <int EPI>
__global__ __launch_bounds__(256) void gemm_bt(
    const u16* __restrict__ A, const u16* __restrict__ B,
    int M, int N, int K, int NX,
    const float* __restrict__ bias,
    const float* __restrict__ resid,
    void* __restrict__ outp) {
  __shared__ u16 As[2][128 * 64];
  __shared__ u16 Bs[2][128 * 64];
  const int tid = threadIdx.x;
  const int wave = tid >> 6, lane = tid & 63;
  const int wr = (wave >> 1) * 64;   // wave row offset in tile
  const int wc = (wave & 1) * 64;    // wave col offset in tile
  const int lrow = lane & 15, lk = lane >> 4;

  // T1: XCD-aware bijective swizzle (nwg % 8 == 0): contiguous chunk per XCD
  const int nwg = gridDim.x;
  const int wg = (blockIdx.x & 7) * (nwg >> 3) + (blockIdx.x >> 3);
  const int bx = wg % NX, by = wg / NX;
  const size_t m0 = (size_t)by * 128;
  const size_t n0 = (size_t)bx * 128;

  f32x4 acc[4][4] = {};

  // stage K-tile into buffer buf. LDS dest LINEAR (gload_lds writes base+lane*16);
  // T2 swizzle applied on the SOURCE address (rule #21): lane l loads global
  // 16B-slot (l&7)^((l>>3)&7) of row seg*8+(l>>3). 8-lane groups still cover one
  // aligned 128B row chunk -> fully coalesced.
  const int srow = lane >> 3;
  const int sslot = (lane & 7) ^ ((lane >> 3) & 7);
  auto STAGE = [&](int buf, int k0) {
#pragma unroll
    for (int c = 0; c < 4; ++c) {
      const int seg = c * 4 + wave;          // 0..15, each = 8 rows
      const int r = seg * 8 + srow;
      llds16(&As[buf][seg * 512], A + (m0 + r) * (size_t)K + (k0 + sslot * 8));
      llds16(&Bs[buf][seg * 512], B + (n0 + r) * (size_t)K + (k0 + sslot * 8));
    }
  };

  const int NT = K >> 6;
  STAGE(0, 0);                                   // 8 vmem in flight

  for (int t = 0; t < NT; ++t) {
    const int cur = t & 1;
    if (t + 1 < NT) {
      STAGE(cur ^ 1, (t + 1) << 6);              // 16 in flight
      asm volatile("s_waitcnt vmcnt(8)" ::: "memory");  // tile t landed; t+1 stays in flight
    } else {
      asm volatile("s_waitcnt vmcnt(0)" ::: "memory");
    }
    __builtin_amdgcn_s_barrier();                // raw barrier: NO vmcnt drain
    asm volatile("" ::: "memory");

    const u16* Ab = &As[cur][0];
    const u16* Bb = &Bs[cur][0];
#pragma unroll
    for (int ks = 0; ks < 2; ++ks) {
      bf16x8 af[4], bfr[4];
      // swizzled read: row R has R&7 == lane&7 for all fragments
#pragma unroll
      for (int m = 0; m < 4; ++m)
        af[m] = *(const bf16x8*)&Ab[(wr + m * 16 + lrow) * 64 +
                                    ((unsigned)(ks * 4 + lk) ^ (lane & 7)) * 8];
#pragma unroll
      for (int n = 0; n < 4; ++n)
        bfr[n] = *(const bf16x8*)&Bb[(wc + n * 16 + lrow) * 64 +
                                     ((unsigned)(ks * 4 + lk) ^ (lane & 7)) * 8];
      __builtin_amdgcn_s_setprio(1);
#pragma unroll
      for (int m = 0; m < 4; ++m)
#pragma unroll
        for (int n = 0; n < 4; ++n)
          acc[m][n] = __builtin_amdgcn_mfma_f32_16x16x32_bf16(af[m], bfr[n],
                                                              acc[m][n], 0, 0, 0);
      __builtin_amdgcn_s_setprio(0);
    }
    asm volatile("s_waitcnt lgkmcnt(0)" ::: "memory");  // all my ds_reads of cur done
    __builtin_amdgcn_s_barrier();                // safe to overwrite cur next iter
    asm volatile("" ::: "memory");
  }

  // epilogue: D row i = 4*(lane>>4)+reg (M dim), col j = lane&15 (N dim)
#pragma unroll
  for (int m = 0; m < 4; ++m) {
    const size_t row_base = m0 + wr + m * 16 + lk * 4;
#pragma unroll
    for (int n = 0; n < 4; ++n) {
      const size_t col = n0 + wc + n * 16 + lrow;
      const float bv = bias[col];
#pragma unroll
      for (int r = 0; r < 4; ++r) {
        const size_t row = row_base + r;
        float v = acc[m][n][r] + bv;
        if (EPI == 1) {
          v = fmaxf(v, 0.0f);
          ((u16*)outp)[row * (size_t)N + col] = f2bf(v);
        } else {
          v += resid[row * (size_t)N + col];
          ((float*)outp)[row * (size_t)N + col] = v;
        }
      }
    }
  }
}

extern "C" void kernel_launch(void* const* d_in, const int* in_sizes, int n_in,
                              void* d_out, int out_size, void* d_ws, size_t ws_size,
                              hipStream_t stream) {
  const float* x         = (const float*)d_in[0];
  const float* down_w    = (const float*)d_in[1];
  const float* down_b    = (const float*)d_in[2];
  const float* up_w      = (const float*)d_in[3];
  const float* up_b      = (const float*)d_in[4];
  const float* ln_g      = (const float*)d_in[5];
  const float* ln_b      = (const float*)d_in[6];
  const float* down_loga = (const float*)d_in[7];
  const float* up_loga   = (const float*)d_in[8];
  const int*   lang      = (const int*)d_in[9];

  const int D = 2048, BNK = 512;
  const int M = in_sizes[0] / D;  // 16384

  char* ws = (char*)d_ws;
  u16* h1  = (u16*)ws;                                   // [M][D] bf16
  u16* h2  = (u16*)(ws + (size_t)M * D * 2);             // [M][BNK] bf16
  u16* dwb = (u16*)(ws + (size_t)M * D * 2 + (size_t)M * BNK * 2);  // [BNK][D]
  u16* uwb = dwb + (size_t)BNK * D;                      // [D][BNK]

  prep_weights<<<(BNK * D) / 256, 256, 0, stream>>>(down_w, up_w, down_loga,
                                                    up_loga, lang, dwb, uwb);
  ln_kernel<<<M, 256, 0, stream>>>(x, ln_g, ln_b, h1);
  const int nwg1 = (BNK / 128) * (M / 128);   // 512
  const int nwg2 = (D / 128) * (M / 128);     // 2048
  gemm_bt<1><<<nwg1, 256, 0, stream>>>(h1, dwb, M, BNK, D, BNK / 128,
                                       down_b, nullptr, h2);
  gemm_bt<2><<<nwg2, 256, 0, stream>>>(h2, uwb, M, D, BNK, D / 128,
                                       up_b, x, d_out);
}

// Round 5
// 153.111 us; speedup vs baseline: 1.1797x; 1.0404x over previous
//
#include <hip/hip_runtime.h>
#include <cstdint>
#include <cstddef>

typedef unsigned short u16;
typedef __attribute__((ext_vector_type(4))) float f32x4;
typedef __attribute__((ext_vector_type(8))) short bf16x8;

#define LN_EPS 1e-5f

__device__ __forceinline__ u16 f2bf(float f) {
  unsigned int u = __float_as_uint(f);
  u += 0x7FFFu + ((u >> 16) & 1u);
  return (u16)(u >> 16);
}

__device__ __forceinline__ float l0gate(float loga) {
  float s = 1.0f / (1.0f + expf(-loga));
  float v = s * 1.2f - 0.1f;   // sigmoid*(zeta-gamma)+gamma, zeta=1.1 gamma=-0.1
  return fminf(fmaxf(v, 0.0f), 1.0f);
}

__device__ __forceinline__ void llds16(u16* lds, const u16* g) {
  __builtin_amdgcn_global_load_lds(
      (const __attribute__((address_space(1))) unsigned int*)g,
      (__attribute__((address_space(3))) unsigned int*)lds, 16, 0, 0);
}

// ---- prep: fold L0 gate into bf16 weights ----
__global__ __launch_bounds__(256) void prep_weights(
    const float* __restrict__ dw, const float* __restrict__ uw,
    const float* __restrict__ dloga, const float* __restrict__ uloga,
    const int* __restrict__ lang,
    u16* __restrict__ dwb, u16* __restrict__ uwb) {
  const int lid = lang[0];
  const unsigned i = blockIdx.x * 256u + threadIdx.x;
  dwb[i] = f2bf(dw[i] * l0gate(dloga[lid * 2048 + (i & 2047u)]));
  uwb[i] = f2bf(uw[i] * l0gate(uloga[lid * 512 + (i & 511u)]));
}

// ---- LayerNorm over D=2048 + bf16 cast; one block per token row ----
__global__ __launch_bounds__(256) void ln_kernel(
    const float* __restrict__ x, const float* __restrict__ g,
    const float* __restrict__ b, u16* __restrict__ h1) {
  const int row = blockIdx.x;
  const int tid = threadIdx.x;
  const float4* xr = (const float4*)(x + (size_t)row * 2048);
  float4 v0 = xr[tid * 2 + 0];
  float4 v1 = xr[tid * 2 + 1];
  float s = v0.x + v0.y + v0.z + v0.w + v1.x + v1.y + v1.z + v1.w;
  float q = v0.x * v0.x + v0.y * v0.y + v0.z * v0.z + v0.w * v0.w +
            v1.x * v1.x + v1.y * v1.y + v1.z * v1.z + v1.w * v1.w;
#pragma unroll
  for (int off = 32; off > 0; off >>= 1) {
    s += __shfl_down(s, off, 64);
    q += __shfl_down(q, off, 64);
  }
  __shared__ float ss[4], sq[4], sstat[2];
  const int wave = tid >> 6, lane = tid & 63;
  if (lane == 0) { ss[wave] = s; sq[wave] = q; }
  __syncthreads();
  if (tid == 0) {
    float S = ss[0] + ss[1] + ss[2] + ss[3];
    float Q = sq[0] + sq[1] + sq[2] + sq[3];
    float mu = S * (1.0f / 2048.0f);
    float var = Q * (1.0f / 2048.0f) - mu * mu;
    sstat[0] = mu;
    sstat[1] = rsqrtf(var + LN_EPS);
  }
  __syncthreads();
  const float mu = sstat[0], rs = sstat[1];
  const float4* g4 = (const float4*)g;
  const float4* b4 = (const float4*)b;
  float4 ga = g4[tid * 2], gb = g4[tid * 2 + 1];
  float4 ba = b4[tid * 2], bb = b4[tid * 2 + 1];
  union { u16 us[8]; uint4 u; } p;
  p.us[0] = f2bf((v0.x - mu) * rs * ga.x + ba.x);
  p.us[1] = f2bf((v0.y - mu) * rs * ga.y + ba.y);
  p.us[2] = f2bf((v0.z - mu) * rs * ga.z + ba.z);
  p.us[3] = f2bf((v0.w - mu) * rs * ga.w + ba.w);
  p.us[4] = f2bf((v1.x - mu) * rs * gb.x + bb.x);
  p.us[5] = f2bf((v1.y - mu) * rs * gb.y + bb.y);
  p.us[6] = f2bf((v1.z - mu) * rs * gb.z + bb.z);
  p.us[7] = f2bf((v1.w - mu) * rs * gb.w + bb.w);
  ((uint4*)(h1 + (size_t)row * 2048))[tid] = p.u;
}

// ---- dbuf bf16 GEMM, counted-vmcnt pipeline + T2 swizzle + T1 XCD swizzle ----
// C[M,N] = A[M,K] * B[N,K]^T, both K-contiguous. LDS-transposed coalesced epilogue.
// EPI=1: +bias, relu, bf16 store.  EPI=2: +bias +resid, f32 store.
template <int EPI>
__global__ __launch_bounds__(256) void gemm_bt(
    const u16* __restrict__ A, const u16* __restrict__ B,
    int M, int N, int K, int NX,
    const float* __restrict__ bias,
    const float* __restrict__ resid,
    void* __restrict__ outp) {
  __shared__ __align__(16) char smem[65536];
  u16* As = (u16*)smem;                 // As[buf] = As + buf*8192 (2 x 16 KB)
  u16* Bs = (u16*)(smem + 32768);       // Bs[buf] = Bs + buf*8192 (2 x 16 KB)
  float* Cs = (float*)smem;             // epilogue alias: 128x128 f32 (64 KB)

  const int tid = threadIdx.x;
  const int wave = tid >> 6, lane = tid & 63;
  const int wr = (wave >> 1) * 64;   // wave row offset in tile
  const int wc = (wave & 1) * 64;    // wave col offset in tile
  const int lrow = lane & 15, lk = lane >> 4;

  // T1: XCD-aware bijective swizzle (nwg % 8 == 0)
  const int nwg = gridDim.x;
  const int wg = (blockIdx.x & 7) * (nwg >> 3) + (blockIdx.x >> 3);
  const int bx = wg % NX, by = wg / NX;
  const size_t m0 = (size_t)by * 128;
  const size_t n0 = (size_t)bx * 128;

  f32x4 acc[4][4] = {};

  // T2 swizzle on SOURCE addr (rule #21), LDS dest linear for global_load_lds
  const int srow = lane >> 3;
  const int sslot = (lane & 7) ^ ((lane >> 3) & 7);
  auto STAGE = [&](int buf, int k0) {
#pragma unroll
    for (int c = 0; c < 4; ++c) {
      const int seg = c * 4 + wave;          // 0..15, each = 8 rows
      const int r = seg * 8 + srow;
      llds16(As + buf * 8192 + seg * 512, A + (m0 + r) * (size_t)K + (k0 + sslot * 8));
      llds16(Bs + buf * 8192 + seg * 512, B + (n0 + r) * (size_t)K + (k0 + sslot * 8));
    }
  };

  const int NT = K >> 6;
  STAGE(0, 0);

  for (int t = 0; t < NT; ++t) {
    const int cur = t & 1;
    if (t + 1 < NT) {
      STAGE(cur ^ 1, (t + 1) << 6);
      asm volatile("s_waitcnt vmcnt(8)" ::: "memory");  // tile t landed; t+1 in flight
    } else {
      asm volatile("s_waitcnt vmcnt(0)" ::: "memory");
    }
    __builtin_amdgcn_s_barrier();
    asm volatile("" ::: "memory");

    const u16* Ab = As + cur * 8192;
    const u16* Bb = Bs + cur * 8192;
#pragma unroll
    for (int ks = 0; ks < 2; ++ks) {
      bf16x8 af[4], bfr[4];
#pragma unroll
      for (int m = 0; m < 4; ++m)
        af[m] = *(const bf16x8*)&Ab[(wr + m * 16 + lrow) * 64 +
                                    ((unsigned)(ks * 4 + lk) ^ (lane & 7)) * 8];
#pragma unroll
      for (int n = 0; n < 4; ++n)
        bfr[n] = *(const bf16x8*)&Bb[(wc + n * 16 + lrow) * 64 +
                                     ((unsigned)(ks * 4 + lk) ^ (lane & 7)) * 8];
      __builtin_amdgcn_s_setprio(1);
#pragma unroll
      for (int m = 0; m < 4; ++m)
#pragma unroll
        for (int n = 0; n < 4; ++n)
          acc[m][n] = __builtin_amdgcn_mfma_f32_16x16x32_bf16(af[m], bfr[n],
                                                              acc[m][n], 0, 0, 0);
      __builtin_amdgcn_s_setprio(0);
    }
    asm volatile("s_waitcnt lgkmcnt(0)" ::: "memory");
    __builtin_amdgcn_s_barrier();
    asm volatile("" ::: "memory");
  }

  // ---- epilogue: acc -> LDS (rotated layout, uniform 2-way banks) -> coalesced out
  // T14: issue resid prefetch BEFORE the LDS write phase; raw barrier (no vmcnt
  // drain) keeps them in flight under the transpose.
  float4 rsd[16];
  if (EPI == 2) {
#pragma unroll
    for (int j = 0; j < 16; ++j) {
      const int flat = tid * 4 + j * 1024;
      const int row = flat >> 7, col = flat & 127;
      rsd[j] = *(const float4*)&resid[(m0 + row) * (size_t)N + n0 + col];
    }
  }

  // write phase: Cs[row][ (col + 8*(row>>2)) & 127 ] = acc + bias
#pragma unroll
  for (int n = 0; n < 4; ++n) {
    const int col = wc + n * 16 + lrow;
    const float bv = bias[n0 + col];
#pragma unroll
    for (int m = 0; m < 4; ++m) {
#pragma unroll
      for (int r = 0; r < 4; ++r) {
        const int row = wr + m * 16 + lk * 4 + r;
        Cs[row * 128 + ((col + ((row >> 2) << 3)) & 127)] = acc[m][n][r] + bv;
      }
    }
  }
  asm volatile("s_waitcnt lgkmcnt(0)" ::: "memory");
  __builtin_amdgcn_s_barrier();
  asm volatile("" ::: "memory");

  if (EPI == 2) {
#pragma unroll
    for (int j = 0; j < 16; ++j) {
      const int flat = tid * 4 + j * 1024;
      const int row = flat >> 7, col = flat & 127;
      const float4 c = *(const float4*)&Cs[row * 128 + ((col + ((row >> 2) << 3)) & 127)];
      float4 o;
      o.x = c.x + rsd[j].x; o.y = c.y + rsd[j].y;
      o.z = c.z + rsd[j].z; o.w = c.w + rsd[j].w;
      *(float4*)&((float*)outp)[(m0 + row) * (size_t)N + n0 + col] = o;
    }
  } else {
    // 256 threads x 8 elems x 8 iters = 16384 = full 128x128 tile
#pragma unroll
    for (int j = 0; j < 8; ++j) {
      const int flat = tid * 8 + j * 2048;
      const int row = flat >> 7, col = flat & 127;
      const int cp = (col + ((row >> 2) << 3)) & 127;   // 8-chunk never wraps
      const float4 c0 = *(const float4*)&Cs[row * 128 + cp];
      const float4 c1 = *(const float4*)&Cs[row * 128 + cp + 4];
      union { u16 us[8]; uint4 u; } p;
      p.us[0] = f2bf(fmaxf(c0.x, 0.0f)); p.us[1] = f2bf(fmaxf(c0.y, 0.0f));
      p.us[2] = f2bf(fmaxf(c0.z, 0.0f)); p.us[3] = f2bf(fmaxf(c0.w, 0.0f));
      p.us[4] = f2bf(fmaxf(c1.x, 0.0f)); p.us[5] = f2bf(fmaxf(c1.y, 0.0f));
      p.us[6] = f2bf(fmaxf(c1.z, 0.0f)); p.us[7] = f2bf(fmaxf(c1.w, 0.0f));
      *(uint4*)&((u16*)outp)[(m0 + row) * (size_t)N + n0 + col] = p.u;
    }
  }
}

extern "C" void kernel_launch(void* const* d_in, const int* in_sizes, int n_in,
                              void* d_out, int out_size, void* d_ws, size_t ws_size,
                              hipStream_t stream) {
  const float* x         = (const float*)d_in[0];
  const float* down_w    = (const float*)d_in[1];
  const float* down_b    = (const float*)d_in[2];
  const float* up_w      = (const float*)d_in[3];
  const float* up_b      = (const float*)d_in[4];
  const float* ln_g      = (const float*)d_in[5];
  const float* ln_b      = (const float*)d_in[6];
  const float* down_loga = (const float*)d_in[7];
  const float* up_loga   = (const float*)d_in[8];
  const int*   lang      = (const int*)d_in[9];

  const int D = 2048, BNK = 512;
  const int M = in_sizes[0] / D;  // 16384

  char* ws = (char*)d_ws;
  u16* h1  = (u16*)ws;                                   // [M][D] bf16
  u16* h2  = (u16*)(ws + (size_t)M * D * 2);             // [M][BNK] bf16
  u16* dwb = (u16*)(ws + (size_t)M * D * 2 + (size_t)M * BNK * 2);  // [BNK][D]
  u16* uwb = dwb + (size_t)BNK * D;                      // [D][BNK]

  prep_weights<<<(BNK * D) / 256, 256, 0, stream>>>(down_w, up_w, down_loga,
                                                    up_loga, lang, dwb, uwb);
  ln_kernel<<<M, 256, 0, stream>>>(x, ln_g, ln_b, h1);
  const int nwg1 = (BNK / 128) * (M / 128);   // 512
  const int nwg2 = (D / 128) * (M / 128);     // 2048
  gemm_bt<1><<<nwg1, 256, 0, stream>>>(h1, dwb, M, BNK, D, BNK / 128,
                                       down_b, nullptr, h2);
  gemm_bt<2><<<nwg2, 256, 0, stream>>>(h2, uwb, M, D, BNK, D / 128,
                                       up_b, x, d_out);
}